// Round 8
// baseline (930.794 us; speedup 1.0000x reference)
//
#include <hip/hip_runtime.h>
#include <hip/hip_fp16.h>
#include <hip/hip_cooperative_groups.h>

namespace cg = cooperative_groups;

#define USER_N   100000
#define ITEM_N   200000
#define LATDIM   128
#define NV4      32                     // float4 per row (f32 rows)
#define NV8      16                     // h8 per row (fp16 rows)
#define N_TOTAL  300000
#define NR_ALL   400000                 // + user-graph rows appended
#define N_EDGES_C  600000
#define UU_EDGES_C 300000
#define NE_ALL   900000
#define SCAN_B   256
#define CONV_T   (N_TOTAL * NV8)        // 4.8M conv work items
#define CONV_Q   (CONV_T / 4)           // 1.2M per phase
#define NCH      ((NR_ALL + SCAN_B - 1) / SCAN_B)   // 1563 scan chunks
#define COOP_BLK 1024

// 16-byte fp16 oct (8 dims/lane, 16 lanes per 128-dim row)
struct alignas(16) h8 { __half2 a, b, c, d; };
struct alignas(8)  Edge { int c; float v; };

typedef float f4_ext __attribute__((ext_vector_type(4)));
typedef int   i4_ext __attribute__((ext_vector_type(4)));
typedef int   i2_ext __attribute__((ext_vector_type(2)));

union H8I { i4_ext i; h8 h; };
union EDI { i2_ext i; Edge e; };

__device__ __forceinline__ float4 nt_load4(const float4* p) {
    f4_ext v = __builtin_nontemporal_load((const f4_ext*)p);
    return make_float4(v.x, v.y, v.z, v.w);
}
__device__ __forceinline__ void nt_store4(float4* p, float4 a) {
    f4_ext v = {a.x, a.y, a.z, a.w};
    __builtin_nontemporal_store(v, (f4_ext*)p);
}
__device__ __forceinline__ h8 nt_load_h8(const h8* p) {
    H8I u; u.i = __builtin_nontemporal_load((const i4_ext*)p);
    return u.h;
}
__device__ __forceinline__ Edge nt_load_edge(const Edge* p) {
    EDI u; u.i = __builtin_nontemporal_load((const i2_ext*)p);
    return u.e;
}

__device__ __forceinline__ h8 to_h8(float4 lo, float4 hi) {
    h8 r;
    r.a = __floats2half2_rn(lo.x, lo.y); r.b = __floats2half2_rn(lo.z, lo.w);
    r.c = __floats2half2_rn(hi.x, hi.y); r.d = __floats2half2_rn(hi.z, hi.w);
    return r;
}
__device__ __forceinline__ void h8_to_f(h8 h, float4& lo, float4& hi) {
    float2 p = __half22float2(h.a), q = __half22float2(h.b);
    float2 s = __half22float2(h.c), t = __half22float2(h.d);
    lo = make_float4(p.x, p.y, q.x, q.y);
    hi = make_float4(s.x, s.y, t.x, t.y);
}
__device__ __forceinline__ void fma4(float4& a, float v, float4 x) {
    a.x += v * x.x; a.y += v * x.y; a.z += v * x.z; a.w += v * x.w;
}
__device__ __forceinline__ float4 add4(float4 a, float4 b) {
    return make_float4(a.x + b.x, a.y + b.y, a.z + b.z, a.w + b.w);
}

// E16 = fp16(concat(uE, iE)); one work item = one h8 (2 float4 loads)
__device__ __forceinline__ void conv_do(int t, const float4* __restrict__ uE,
                                        const float4* __restrict__ iE,
                                        h8* __restrict__ E16) {
    if (t < 0 || t >= CONV_T) return;
    int f4i = t * 2;
    const int ub = USER_N * NV4;
    float4 lo, hi;
    if (f4i < ub) { lo = nt_load4(uE + f4i);        hi = nt_load4(uE + f4i + 1); }
    else          { lo = nt_load4(iE + (f4i - ub)); hi = nt_load4(iE + (f4i - ub) + 1); }
    E16[t] = to_h8(lo, hi);
}

// ---------------------------------------------------------------------------
// Cooperative kernel: CSR build (hist -> scan -> scatter) with the E16
// conversion overlapped into every phase. Replaces memset + 5 launches.
// ---------------------------------------------------------------------------
__global__ void __launch_bounds__(256, 4)
csr_conv_coop(const float4* __restrict__ uE, const float4* __restrict__ iE,
              h8* __restrict__ E16,
              const int* __restrict__ ar, const int* __restrict__ ac,
              const float* __restrict__ av,
              const int* __restrict__ ur, const int* __restrict__ uc,
              const float* __restrict__ uv,
              int* __restrict__ cnt, int* __restrict__ rptr,
              int* __restrict__ cursor, int* __restrict__ bsum,
              Edge* __restrict__ edges) {
    cg::grid_group grid = cg::this_grid();
    __shared__ int s[SCAN_B];
    __shared__ int carry;

    const int NT  = COOP_BLK * 256;
    const int tid = blockIdx.x * blockDim.x + threadIdx.x;

    // ---- phase A: zero cnt  +  conv quarter 0 ----
    for (int i = tid; i < NR_ALL; i += NT) cnt[i] = 0;
    for (int t = tid; t < CONV_Q; t += NT) conv_do(t, uE, iE, E16);
    grid.sync();

    // ---- phase B: histogram  +  conv quarter 1 ----
    for (int i = tid; i < NE_ALL; i += NT) {
        if (i < N_EDGES_C) atomicAdd(&cnt[ar[i]], 1);
        else               atomicAdd(&cnt[ur[i - N_EDGES_C] + N_TOTAL], 1);
    }
    for (int t = CONV_Q + tid; t < 2 * CONV_Q; t += NT) conv_do(t, uE, iE, E16);
    grid.sync();

    // ---- phase C: per-chunk exclusive scan  +  conv quarter 2 ----
    for (int ch = blockIdx.x; ch < NCH; ch += gridDim.x) {
        int i = ch * SCAN_B + threadIdx.x;
        int v = (i < NR_ALL) ? cnt[i] : 0;
        s[threadIdx.x] = v;
        __syncthreads();
        for (int off = 1; off < SCAN_B; off <<= 1) {
            int t2 = (threadIdx.x >= off) ? s[threadIdx.x - off] : 0;
            __syncthreads();
            s[threadIdx.x] += t2;
            __syncthreads();
        }
        if (i < NR_ALL) rptr[i] = s[threadIdx.x] - v;        // exclusive-in-chunk
        if (threadIdx.x == SCAN_B - 1) bsum[ch] = s[threadIdx.x];
        __syncthreads();
    }
    for (int t = 2 * CONV_Q + tid; t < 3 * CONV_Q; t += NT) conv_do(t, uE, iE, E16);
    grid.sync();

    // ---- phase D: block 0 scans bsum; all other blocks do conv quarter 3 ----
    if (blockIdx.x == 0) {
        if (threadIdx.x == 0) carry = 0;
        __syncthreads();
        for (int base = 0; base < NCH; base += SCAN_B) {
            int i = base + threadIdx.x;
            int v = (i < NCH) ? bsum[i] : 0;
            s[threadIdx.x] = v;
            __syncthreads();
            for (int off = 1; off < SCAN_B; off <<= 1) {
                int t2 = (threadIdx.x >= off) ? s[threadIdx.x - off] : 0;
                __syncthreads();
                s[threadIdx.x] += t2;
                __syncthreads();
            }
            if (i < NCH) bsum[i] = s[threadIdx.x] - v + carry;
            __syncthreads();
            if (threadIdx.x == 0) carry += s[SCAN_B - 1];
            __syncthreads();
        }
    } else {
        int t = 3 * CONV_Q + (blockIdx.x - 1) * 256 + (int)threadIdx.x;
        int stride = (COOP_BLK - 1) * 256;
        for (; t < CONV_T; t += stride) conv_do(t, uE, iE, E16);
    }
    grid.sync();

    // ---- phase E: add chunk prefixes, init cursor ----
    for (int i = tid; i < NR_ALL; i += NT) {
        int v = rptr[i] + bsum[i / SCAN_B];
        rptr[i]   = v;
        cursor[i] = v;
    }
    if (tid == 0) rptr[NR_ALL] = NE_ALL;
    grid.sync();

    // ---- phase F: scatter edges into CSR order ----
    for (int i = tid; i < NE_ALL; i += NT) {
        int r; Edge ed;
        if (i < N_EDGES_C) { r = ar[i];             ed.c = ac[i];           ed.v = av[i]; }
        else               { int j = i - N_EDGES_C; r = ur[j] + N_TOTAL; ed.c = uc[j] + N_TOTAL; ed.v = uv[j]; }
        int pos = atomicAdd(&cursor[r], 1);
        edges[pos] = ed;
    }
}

// col c -> row in E16 (user-graph cols shifted by N_TOTAL)
__device__ __forceinline__ int e16_row(int c) {
    return (c < N_TOTAL) ? c : c - N_TOTAL;
}

// ---------------------------------------------------------------------------
// pass1: l1 = A*e0 gathering h8 rows from E16. Cached stores (cur1 is
// pass2's gather table — round-7 nt-store experiment regressed).
// ---------------------------------------------------------------------------
__global__ void spmm_pass1(const int* __restrict__ rptr,
                           const Edge* __restrict__ edges,
                           const h8* __restrict__ E16,
                           h8* __restrict__ cur1) {
    int t = blockIdx.x * blockDim.x + threadIdx.x;
    int r = t >> 4, sub = t & 15;
    if (r >= NR_ALL) return;
    int e0 = rptr[r], e1 = rptr[r + 1];

    float4 a0l = make_float4(0,0,0,0), a0h = a0l, a1l = a0l, a1h = a0l;
    int e = e0;
    for (; e + 2 <= e1; e += 2) {
        Edge d0 = edges[e], d1 = edges[e + 1];
        h8 h0 = E16[(size_t)e16_row(d0.c) * NV8 + sub];
        h8 h1 = E16[(size_t)e16_row(d1.c) * NV8 + sub];
        float4 lo, hi;
        h8_to_f(h0, lo, hi); fma4(a0l, d0.v, lo); fma4(a0h, d0.v, hi);
        h8_to_f(h1, lo, hi); fma4(a1l, d1.v, lo); fma4(a1h, d1.v, hi);
    }
    if (e < e1) {
        Edge d0 = edges[e];
        h8 h0 = E16[(size_t)e16_row(d0.c) * NV8 + sub];
        float4 lo, hi;
        h8_to_f(h0, lo, hi); fma4(a0l, d0.v, lo); fma4(a0h, d0.v, hi);
    }
    cur1[(size_t)r * NV8 + sub] = to_h8(add4(a0l, a1l), add4(a0h, a1h));
}

// ---------------------------------------------------------------------------
// pass2: l2 = A*l1 (gather cur1, cached). Main rows -> cur2 (cached store:
// it is pass3's gather table). User rows -> uacc = e0+l1+l2 (nt f32).
// ---------------------------------------------------------------------------
__global__ void spmm_pass2(const int* __restrict__ rptr,
                           const Edge* __restrict__ edges,
                           const h8* __restrict__ cur1,
                           const h8* __restrict__ E16,
                           h8* __restrict__ cur2,
                           float4* __restrict__ uacc) {
    int t = blockIdx.x * blockDim.x + threadIdx.x;
    int r = t >> 4, sub = t & 15;
    if (r >= NR_ALL) return;
    int e0 = rptr[r], e1 = rptr[r + 1];

    float4 a0l = make_float4(0,0,0,0), a0h = a0l, a1l = a0l, a1h = a0l;
    int e = e0;
    for (; e + 2 <= e1; e += 2) {
        Edge d0 = edges[e], d1 = edges[e + 1];
        h8 h0 = cur1[(size_t)d0.c * NV8 + sub];
        h8 h1 = cur1[(size_t)d1.c * NV8 + sub];
        float4 lo, hi;
        h8_to_f(h0, lo, hi); fma4(a0l, d0.v, lo); fma4(a0h, d0.v, hi);
        h8_to_f(h1, lo, hi); fma4(a1l, d1.v, lo); fma4(a1h, d1.v, hi);
    }
    if (e < e1) {
        Edge d0 = edges[e];
        h8 h0 = cur1[(size_t)d0.c * NV8 + sub];
        float4 lo, hi;
        h8_to_f(h0, lo, hi); fma4(a0l, d0.v, lo); fma4(a0h, d0.v, hi);
    }
    float4 al = add4(a0l, a1l), ah = add4(a0h, a1h);

    size_t o = (size_t)r * NV8 + sub;
    if (r < N_TOTAL) {
        cur2[o] = to_h8(al, ah);
    } else {
        int ur = r - N_TOTAL;
        float4 u0l, u0h, l1l, l1h;
        h8_to_f(E16[(size_t)ur * NV8 + sub], u0l, u0h);
        h8_to_f(cur1[o], l1l, l1h);
        size_t of4 = (size_t)ur * NV4 + sub * 2;
        nt_store4(uacc + of4,     add4(add4(u0l, l1l), al));
        nt_store4(uacc + of4 + 1, add4(add4(u0h, l1h), ah));
    }
}

// ---------------------------------------------------------------------------
// pass3 (main rows): l3 = A*l2 (gather cur2, cached); acc = e0+l1+l2+l3
// (nt f32 stores). E16/cur1/edges are last-use -> nt loads.
// ---------------------------------------------------------------------------
__global__ void spmm_pass3(const int* __restrict__ rptr,
                           const Edge* __restrict__ edges,
                           const h8* __restrict__ cur2,
                           const h8* __restrict__ cur1,
                           const h8* __restrict__ E16,
                           float4* __restrict__ acc) {
    int t = blockIdx.x * blockDim.x + threadIdx.x;
    int r = t >> 4, sub = t & 15;
    if (r >= N_TOTAL) return;
    int e0 = rptr[r], e1 = rptr[r + 1];

    float4 a0l = make_float4(0,0,0,0), a0h = a0l, a1l = a0l, a1h = a0l;
    int e = e0;
    for (; e + 2 <= e1; e += 2) {
        Edge d0 = nt_load_edge(edges + e), d1 = nt_load_edge(edges + e + 1);
        h8 h0 = cur2[(size_t)d0.c * NV8 + sub];
        h8 h1 = cur2[(size_t)d1.c * NV8 + sub];
        float4 lo, hi;
        h8_to_f(h0, lo, hi); fma4(a0l, d0.v, lo); fma4(a0h, d0.v, hi);
        h8_to_f(h1, lo, hi); fma4(a1l, d1.v, lo); fma4(a1h, d1.v, hi);
    }
    if (e < e1) {
        Edge d0 = nt_load_edge(edges + e);
        h8 h0 = cur2[(size_t)d0.c * NV8 + sub];
        float4 lo, hi;
        h8_to_f(h0, lo, hi); fma4(a0l, d0.v, lo); fma4(a0h, d0.v, hi);
    }
    float4 al = add4(a0l, a1l), ah = add4(a0h, a1h);

    size_t o = (size_t)r * NV8 + sub;
    float4 ezl, ezh, l1l, l1h, l2l, l2h;
    h8_to_f(nt_load_h8(E16 + o),  ezl, ezh);
    h8_to_f(nt_load_h8(cur1 + o), l1l, l1h);
    h8_to_f(cur2[o], l2l, l2h);

    size_t of4 = (size_t)r * NV4 + sub * 2;
    nt_store4(acc + of4,     add4(add4(ezl, l1l), add4(l2l, al)));
    nt_store4(acc + of4 + 1, add4(add4(ezh, l1h), add4(l2h, ah)));
}

// ---------------------------------------------------------------------------
extern "C" void kernel_launch(void* const* d_in, const int* in_sizes, int n_in,
                              void* d_out, int out_size, void* d_ws, size_t ws_size,
                              hipStream_t stream) {
    const float* uE    = (const float*)d_in[0];
    const float* iE    = (const float*)d_in[1];
    const int*   arows = (const int*)  d_in[2];
    const int*   acols = (const int*)  d_in[3];
    const float* avals = (const float*)d_in[4];
    const int*   urows = (const int*)  d_in[5];
    const int*   ucols = (const int*)  d_in[6];
    const float* uvals = (const float*)d_in[7];

    float* acc  = (float*)d_out;                              // N_TOTAL x 128 f32
    float* uacc = acc + (size_t)N_TOTAL * LATDIM;             // USER_N x 128 f32

    // workspace layout
    h8*    E16  = (h8*)d_ws;                                  // N_TOTAL*NV8  (76.8 MB)
    h8*    cur1 = E16 + (size_t)N_TOTAL * NV8;                // NR_ALL*NV8   (102.4 MB)
    h8*    cur2 = cur1 + (size_t)NR_ALL * NV8;                // N_TOTAL*NV8  (76.8 MB)
    int*   cnt  = (int*)(cur2 + (size_t)N_TOTAL * NV8);       // NR_ALL
    int*   rptr = cnt + NR_ALL;                               // NR_ALL+1
    int*   curp = rptr + NR_ALL + 1;                          // NR_ALL
    int*   bsum = curp + NR_ALL;                              // 4096
    Edge*  edges = (Edge*)(bsum + 4096);                      // NE_ALL (7.2 MB)

    const int TB = 256;
    const float4* uE4 = (const float4*)uE;
    const float4* iE4 = (const float4*)iE;

    // ---- cooperative CSR build + E16 conversion (single launch) ----
    {
        void* params[] = {
            (void*)&uE4, (void*)&iE4, (void*)&E16,
            (void*)&arows, (void*)&acols, (void*)&avals,
            (void*)&urows, (void*)&ucols, (void*)&uvals,
            (void*)&cnt, (void*)&rptr, (void*)&curp, (void*)&bsum, (void*)&edges
        };
        hipLaunchCooperativeKernel((void*)csr_conv_coop,
                                   dim3(COOP_BLK), dim3(TB), params, 0, stream);
    }

    // ---- three fused SpMM passes (16 lanes/row) ----
    {
        int threads = NR_ALL * NV8;
        int grid = (threads + TB - 1) / TB;
        spmm_pass1<<<grid, TB, 0, stream>>>(rptr, edges, E16, cur1);
        spmm_pass2<<<grid, TB, 0, stream>>>(rptr, edges, cur1, E16,
                                            cur2, (float4*)uacc);
    }
    {
        int threads = N_TOTAL * NV8;
        int grid = (threads + TB - 1) / TB;
        spmm_pass3<<<grid, TB, 0, stream>>>(rptr, edges, cur2, cur1, E16,
                                            (float4*)acc);
    }
}

// Round 9
// 352.766 us; speedup vs baseline: 2.6386x; 2.6386x over previous
//
#include <hip/hip_runtime.h>
#include <hip/hip_fp16.h>

#define USER_N   100000
#define ITEM_N   200000
#define LATDIM   128
#define NV4      32                     // float4 per row (f32 rows)
#define NV8      16                     // h8 per row (fp16 rows)
#define N_TOTAL  300000
#define NR_ALL   400000                 // + user-graph rows appended
#define N_EDGES_C  600000
#define UU_EDGES_C 300000
#define NE_ALL   900000
#define SCAN_B   256
#define CONV_T   (N_TOTAL * NV8)        // 4.8M conv work items
#define CONV_BLK 4688                   // blocks per conv chunk
#define CONV_CS  (CONV_BLK * 256)       // 1,200,128 threads per chunk
#define HIST_BLK ((NE_ALL + 255) / 256)     // 3516
#define SCANB_BLK ((NR_ALL + SCAN_B - 1) / SCAN_B)  // 1563

// 16-byte fp16 oct (8 dims/lane, 16 lanes per 128-dim row)
struct alignas(16) h8 { __half2 a, b, c, d; };
struct alignas(8)  Edge { int c; float v; };

typedef float f4_ext __attribute__((ext_vector_type(4)));
typedef int   i4_ext __attribute__((ext_vector_type(4)));
typedef int   i2_ext __attribute__((ext_vector_type(2)));

union H8I { i4_ext i; h8 h; };
union EDI { i2_ext i; Edge e; };

__device__ __forceinline__ float4 nt_load4(const float4* p) {
    f4_ext v = __builtin_nontemporal_load((const f4_ext*)p);
    return make_float4(v.x, v.y, v.z, v.w);
}
__device__ __forceinline__ void nt_store4(float4* p, float4 a) {
    f4_ext v = {a.x, a.y, a.z, a.w};
    __builtin_nontemporal_store(v, (f4_ext*)p);
}
__device__ __forceinline__ h8 nt_load_h8(const h8* p) {
    H8I u; u.i = __builtin_nontemporal_load((const i4_ext*)p);
    return u.h;
}
__device__ __forceinline__ Edge nt_load_edge(const Edge* p) {
    EDI u; u.i = __builtin_nontemporal_load((const i2_ext*)p);
    return u.e;
}

__device__ __forceinline__ h8 to_h8(float4 lo, float4 hi) {
    h8 r;
    r.a = __floats2half2_rn(lo.x, lo.y); r.b = __floats2half2_rn(lo.z, lo.w);
    r.c = __floats2half2_rn(hi.x, hi.y); r.d = __floats2half2_rn(hi.z, hi.w);
    return r;
}
__device__ __forceinline__ void h8_to_f(h8 h, float4& lo, float4& hi) {
    float2 p = __half22float2(h.a), q = __half22float2(h.b);
    float2 s = __half22float2(h.c), t = __half22float2(h.d);
    lo = make_float4(p.x, p.y, q.x, q.y);
    hi = make_float4(s.x, s.y, t.x, t.y);
}
__device__ __forceinline__ void fma4(float4& a, float v, float4 x) {
    a.x += v * x.x; a.y += v * x.y; a.z += v * x.z; a.w += v * x.w;
}
__device__ __forceinline__ float4 add4(float4 a, float4 b) {
    return make_float4(a.x + b.x, a.y + b.y, a.z + b.z, a.w + b.w);
}

// E16 = fp16(concat(uE, iE)); one work item = one h8 (2 float4 loads)
__device__ __forceinline__ void conv_do(int t, const float4* __restrict__ uE,
                                        const float4* __restrict__ iE,
                                        h8* __restrict__ E16) {
    if (t < 0 || t >= CONV_T) return;
    int f4i = t * 2;
    const int ub = USER_N * NV4;
    float4 lo, hi;
    if (f4i < ub) { lo = nt_load4(uE + f4i);        hi = nt_load4(uE + f4i + 1); }
    else          { lo = nt_load4(iE + (f4i - ub)); hi = nt_load4(iE + (f4i - ub) + 1); }
    E16[t] = to_h8(lo, hi);
}

// ---------------------------------------------------------------------------
// K2: histogram (blocks [0,HIST_BLK)) + conv chunk 0
// ---------------------------------------------------------------------------
__global__ void hist_convA(const int* __restrict__ ar, const int* __restrict__ ur,
                           int* __restrict__ cnt,
                           const float4* __restrict__ uE, const float4* __restrict__ iE,
                           h8* __restrict__ E16) {
    if (blockIdx.x < HIST_BLK) {
        int i = blockIdx.x * blockDim.x + threadIdx.x;
        if (i < N_EDGES_C)   atomicAdd(&cnt[ar[i]], 1);
        else if (i < NE_ALL) atomicAdd(&cnt[ur[i - N_EDGES_C] + N_TOTAL], 1);
    } else {
        conv_do((blockIdx.x - HIST_BLK) * 256 + (int)threadIdx.x, uE, iE, E16);
    }
}

// ---------------------------------------------------------------------------
// K3: per-block exclusive scan (blocks [0,SCANB_BLK)) + conv chunk 1
// ---------------------------------------------------------------------------
__global__ void scanblock_convB(const int* __restrict__ cnt,
                                int* __restrict__ rptr, int* __restrict__ bsum,
                                const float4* __restrict__ uE, const float4* __restrict__ iE,
                                h8* __restrict__ E16) {
    if (blockIdx.x < SCANB_BLK) {
        __shared__ int s[SCAN_B];
        int i = blockIdx.x * SCAN_B + threadIdx.x;
        int v = (i < NR_ALL) ? cnt[i] : 0;
        s[threadIdx.x] = v;
        __syncthreads();
        for (int off = 1; off < SCAN_B; off <<= 1) {
            int t = (threadIdx.x >= off) ? s[threadIdx.x - off] : 0;
            __syncthreads();
            s[threadIdx.x] += t;
            __syncthreads();
        }
        if (i < NR_ALL) rptr[i] = s[threadIdx.x] - v;
        if (threadIdx.x == SCAN_B - 1) bsum[blockIdx.x] = s[threadIdx.x];
    } else {
        conv_do((blockIdx.x - SCANB_BLK) * 256 + (int)threadIdx.x + CONV_CS,
                uE, iE, E16);
    }
}

// K4: single-block scan of block sums (tiny, unchanged)
__global__ void scan_bsum_kernel(int* __restrict__ bsum, int nb) {
    __shared__ int s[SCAN_B];
    __shared__ int carry;
    if (threadIdx.x == 0) carry = 0;
    __syncthreads();
    for (int base = 0; base < nb; base += SCAN_B) {
        int i = base + threadIdx.x;
        int v = (i < nb) ? bsum[i] : 0;
        s[threadIdx.x] = v;
        __syncthreads();
        for (int off = 1; off < SCAN_B; off <<= 1) {
            int t = (threadIdx.x >= off) ? s[threadIdx.x - off] : 0;
            __syncthreads();
            s[threadIdx.x] += t;
            __syncthreads();
        }
        if (i < nb) bsum[i] = s[threadIdx.x] - v + carry;
        __syncthreads();
        if (threadIdx.x == 0) carry += s[SCAN_B - 1];
        __syncthreads();
    }
}

// ---------------------------------------------------------------------------
// K5: add block prefixes, init cursor (blocks [0,SCANB_BLK)) + conv chunk 2
// ---------------------------------------------------------------------------
__global__ void scanadd_convC(int* __restrict__ rptr, const int* __restrict__ bsum,
                              int* __restrict__ cursor,
                              const float4* __restrict__ uE, const float4* __restrict__ iE,
                              h8* __restrict__ E16) {
    if (blockIdx.x < SCANB_BLK) {
        int i = blockIdx.x * blockDim.x + threadIdx.x;
        if (i < NR_ALL) {
            int v = rptr[i] + bsum[i / SCAN_B];
            rptr[i]   = v;
            cursor[i] = v;
        }
        if (i == 0) rptr[NR_ALL] = NE_ALL;
    } else {
        conv_do((blockIdx.x - SCANB_BLK) * 256 + (int)threadIdx.x + 2 * CONV_CS,
                uE, iE, E16);
    }
}

// ---------------------------------------------------------------------------
// K6: scatter edges into CSR order (blocks [0,HIST_BLK)) + conv chunk 3
// ---------------------------------------------------------------------------
__global__ void scatter_convD(const int* __restrict__ ar, const int* __restrict__ ac,
                              const float* __restrict__ av,
                              const int* __restrict__ ur, const int* __restrict__ uc,
                              const float* __restrict__ uv,
                              int* __restrict__ cursor, Edge* __restrict__ edges,
                              const float4* __restrict__ uE, const float4* __restrict__ iE,
                              h8* __restrict__ E16) {
    if (blockIdx.x < HIST_BLK) {
        int i = blockIdx.x * blockDim.x + threadIdx.x;
        int r; Edge ed;
        if (i < N_EDGES_C)   { r = ar[i];             ed.c = ac[i];           ed.v = av[i]; }
        else if (i < NE_ALL) { int j = i - N_EDGES_C; r = ur[j] + N_TOTAL; ed.c = uc[j] + N_TOTAL; ed.v = uv[j]; }
        else return;
        int pos = atomicAdd(&cursor[r], 1);
        edges[pos] = ed;
    } else {
        conv_do((blockIdx.x - HIST_BLK) * 256 + (int)threadIdx.x + 3 * CONV_CS,
                uE, iE, E16);
    }
}

// col c -> row in E16 (user-graph cols shifted by N_TOTAL)
__device__ __forceinline__ int e16_row(int c) {
    return (c < N_TOTAL) ? c : c - N_TOTAL;
}

// ---------------------------------------------------------------------------
// pass1: l1 = A*e0 gathering h8 rows from E16. Cached store of cur1 (it is
// pass2's gather table — r7 nt-store experiment regressed).
// ---------------------------------------------------------------------------
__global__ void spmm_pass1(const int* __restrict__ rptr,
                           const Edge* __restrict__ edges,
                           const h8* __restrict__ E16,
                           h8* __restrict__ cur1) {
    int t = blockIdx.x * blockDim.x + threadIdx.x;
    int r = t >> 4, sub = t & 15;
    if (r >= NR_ALL) return;
    int e0 = rptr[r], e1 = rptr[r + 1];

    float4 a0l = make_float4(0,0,0,0), a0h = a0l, a1l = a0l, a1h = a0l;
    int e = e0;
    for (; e + 2 <= e1; e += 2) {
        Edge d0 = edges[e], d1 = edges[e + 1];
        h8 h0 = E16[(size_t)e16_row(d0.c) * NV8 + sub];
        h8 h1 = E16[(size_t)e16_row(d1.c) * NV8 + sub];
        float4 lo, hi;
        h8_to_f(h0, lo, hi); fma4(a0l, d0.v, lo); fma4(a0h, d0.v, hi);
        h8_to_f(h1, lo, hi); fma4(a1l, d1.v, lo); fma4(a1h, d1.v, hi);
    }
    if (e < e1) {
        Edge d0 = edges[e];
        h8 h0 = E16[(size_t)e16_row(d0.c) * NV8 + sub];
        float4 lo, hi;
        h8_to_f(h0, lo, hi); fma4(a0l, d0.v, lo); fma4(a0h, d0.v, hi);
    }
    cur1[(size_t)r * NV8 + sub] = to_h8(add4(a0l, a1l), add4(a0h, a1h));
}

// ---------------------------------------------------------------------------
// pass2: l2 = A*l1 (gather cur1, cached). Main rows -> cur2 (cached store:
// it is pass3's gather table). User rows -> uacc = e0+l1+l2 (nt f32).
// ---------------------------------------------------------------------------
__global__ void spmm_pass2(const int* __restrict__ rptr,
                           const Edge* __restrict__ edges,
                           const h8* __restrict__ cur1,
                           const h8* __restrict__ E16,
                           h8* __restrict__ cur2,
                           float4* __restrict__ uacc) {
    int t = blockIdx.x * blockDim.x + threadIdx.x;
    int r = t >> 4, sub = t & 15;
    if (r >= NR_ALL) return;
    int e0 = rptr[r], e1 = rptr[r + 1];

    float4 a0l = make_float4(0,0,0,0), a0h = a0l, a1l = a0l, a1h = a0l;
    int e = e0;
    for (; e + 2 <= e1; e += 2) {
        Edge d0 = edges[e], d1 = edges[e + 1];
        h8 h0 = cur1[(size_t)d0.c * NV8 + sub];
        h8 h1 = cur1[(size_t)d1.c * NV8 + sub];
        float4 lo, hi;
        h8_to_f(h0, lo, hi); fma4(a0l, d0.v, lo); fma4(a0h, d0.v, hi);
        h8_to_f(h1, lo, hi); fma4(a1l, d1.v, lo); fma4(a1h, d1.v, hi);
    }
    if (e < e1) {
        Edge d0 = edges[e];
        h8 h0 = cur1[(size_t)d0.c * NV8 + sub];
        float4 lo, hi;
        h8_to_f(h0, lo, hi); fma4(a0l, d0.v, lo); fma4(a0h, d0.v, hi);
    }
    float4 al = add4(a0l, a1l), ah = add4(a0h, a1h);

    size_t o = (size_t)r * NV8 + sub;
    if (r < N_TOTAL) {
        cur2[o] = to_h8(al, ah);
    } else {
        int ur = r - N_TOTAL;
        float4 u0l, u0h, l1l, l1h;
        h8_to_f(E16[(size_t)ur * NV8 + sub], u0l, u0h);
        h8_to_f(cur1[o], l1l, l1h);
        size_t of4 = (size_t)ur * NV4 + sub * 2;
        nt_store4(uacc + of4,     add4(add4(u0l, l1l), al));
        nt_store4(uacc + of4 + 1, add4(add4(u0h, l1h), ah));
    }
}

// ---------------------------------------------------------------------------
// pass3 (main rows): l3 = A*l2 (gather cur2, cached); acc = e0+l1+l2+l3
// (nt f32 stores). E16/cur1/edges are last-use -> nt loads.
// ---------------------------------------------------------------------------
__global__ void spmm_pass3(const int* __restrict__ rptr,
                           const Edge* __restrict__ edges,
                           const h8* __restrict__ cur2,
                           const h8* __restrict__ cur1,
                           const h8* __restrict__ E16,
                           float4* __restrict__ acc) {
    int t = blockIdx.x * blockDim.x + threadIdx.x;
    int r = t >> 4, sub = t & 15;
    if (r >= N_TOTAL) return;
    int e0 = rptr[r], e1 = rptr[r + 1];

    float4 a0l = make_float4(0,0,0,0), a0h = a0l, a1l = a0l, a1h = a0l;
    int e = e0;
    for (; e + 2 <= e1; e += 2) {
        Edge d0 = nt_load_edge(edges + e), d1 = nt_load_edge(edges + e + 1);
        h8 h0 = cur2[(size_t)d0.c * NV8 + sub];
        h8 h1 = cur2[(size_t)d1.c * NV8 + sub];
        float4 lo, hi;
        h8_to_f(h0, lo, hi); fma4(a0l, d0.v, lo); fma4(a0h, d0.v, hi);
        h8_to_f(h1, lo, hi); fma4(a1l, d1.v, lo); fma4(a1h, d1.v, hi);
    }
    if (e < e1) {
        Edge d0 = nt_load_edge(edges + e);
        h8 h0 = cur2[(size_t)d0.c * NV8 + sub];
        float4 lo, hi;
        h8_to_f(h0, lo, hi); fma4(a0l, d0.v, lo); fma4(a0h, d0.v, hi);
    }
    float4 al = add4(a0l, a1l), ah = add4(a0h, a1h);

    size_t o = (size_t)r * NV8 + sub;
    float4 ezl, ezh, l1l, l1h, l2l, l2h;
    h8_to_f(nt_load_h8(E16 + o),  ezl, ezh);
    h8_to_f(nt_load_h8(cur1 + o), l1l, l1h);
    h8_to_f(cur2[o], l2l, l2h);

    size_t of4 = (size_t)r * NV4 + sub * 2;
    nt_store4(acc + of4,     add4(add4(ezl, l1l), add4(l2l, al)));
    nt_store4(acc + of4 + 1, add4(add4(ezh, l1h), add4(l2h, ah)));
}

// ---------------------------------------------------------------------------
extern "C" void kernel_launch(void* const* d_in, const int* in_sizes, int n_in,
                              void* d_out, int out_size, void* d_ws, size_t ws_size,
                              hipStream_t stream) {
    const float* uE    = (const float*)d_in[0];
    const float* iE    = (const float*)d_in[1];
    const int*   arows = (const int*)  d_in[2];
    const int*   acols = (const int*)  d_in[3];
    const float* avals = (const float*)d_in[4];
    const int*   urows = (const int*)  d_in[5];
    const int*   ucols = (const int*)  d_in[6];
    const float* uvals = (const float*)d_in[7];

    float* acc  = (float*)d_out;                              // N_TOTAL x 128 f32
    float* uacc = acc + (size_t)N_TOTAL * LATDIM;             // USER_N x 128 f32

    // workspace layout
    h8*    E16  = (h8*)d_ws;                                  // N_TOTAL*NV8  (76.8 MB)
    h8*    cur1 = E16 + (size_t)N_TOTAL * NV8;                // NR_ALL*NV8   (102.4 MB)
    h8*    cur2 = cur1 + (size_t)NR_ALL * NV8;                // N_TOTAL*NV8  (76.8 MB)
    int*   cnt  = (int*)(cur2 + (size_t)N_TOTAL * NV8);       // NR_ALL
    int*   rptr = cnt + NR_ALL;                               // NR_ALL+1
    int*   curp = rptr + NR_ALL + 1;                          // NR_ALL
    int*   bsum = curp + NR_ALL;                              // 4096
    Edge*  edges = (Edge*)(bsum + 4096);                      // NE_ALL (7.2 MB)

    const int TB = 256;
    const float4* uE4 = (const float4*)uE;
    const float4* iE4 = (const float4*)iE;

    hipMemsetAsync(cnt, 0, NR_ALL * sizeof(int), stream);

    // ---- CSR build with conv (E16) hidden underneath ----
    hist_convA<<<HIST_BLK + CONV_BLK, TB, 0, stream>>>(arows, urows, cnt, uE4, iE4, E16);
    scanblock_convB<<<SCANB_BLK + CONV_BLK, SCAN_B, 0, stream>>>(cnt, rptr, bsum, uE4, iE4, E16);
    scan_bsum_kernel<<<1, SCAN_B, 0, stream>>>(bsum, SCANB_BLK);
    scanadd_convC<<<SCANB_BLK + CONV_BLK, TB, 0, stream>>>(rptr, bsum, curp, uE4, iE4, E16);
    scatter_convD<<<HIST_BLK + CONV_BLK, TB, 0, stream>>>(
        arows, acols, avals, urows, ucols, uvals, curp, edges, uE4, iE4, E16);

    // ---- three fused SpMM passes (16 lanes/row) ----
    {
        int threads = NR_ALL * NV8;
        int grid = (threads + TB - 1) / TB;
        spmm_pass1<<<grid, TB, 0, stream>>>(rptr, edges, E16, cur1);
        spmm_pass2<<<grid, TB, 0, stream>>>(rptr, edges, cur1, E16,
                                            cur2, (float4*)uacc);
    }
    {
        int threads = N_TOTAL * NV8;
        int grid = (threads + TB - 1) / TB;
        spmm_pass3<<<grid, TB, 0, stream>>>(rptr, edges, cur2, cur1, E16,
                                            (float4*)acc);
    }
}

// Round 10
// 348.160 us; speedup vs baseline: 2.6735x; 1.0132x over previous
//
#include <hip/hip_runtime.h>
#include <hip/hip_fp16.h>

#define USER_N   100000
#define ITEM_N   200000
#define LATDIM   128
#define NV4      32                     // float4 per row (f32 rows)
#define NV8      16                     // h8 per row (fp16 rows)
#define N_TOTAL  300000
#define NR_ALL   400000                 // + user-graph rows appended
#define N_EDGES_C  600000
#define UU_EDGES_C 300000
#define NE_ALL   900000
#define SCAN_B   256
#define CONV_T   (N_TOTAL * NV8)        // 4.8M conv work items
#define CONV_BLK 4688                   // blocks per conv chunk
#define CONV_CS  (CONV_BLK * 256)       // 1,200,128 threads per chunk
#define HIST_BLK ((NE_ALL + 255) / 256)     // 3516
#define SCANB_BLK ((NR_ALL + SCAN_B - 1) / SCAN_B)  // 1563

// 16-byte fp16 oct (8 dims/lane, 16 lanes per 128-dim row)
struct alignas(16) h8 { __half2 a, b, c, d; };
struct alignas(8)  Edge { int c; float v; };

typedef float f4_ext __attribute__((ext_vector_type(4)));
typedef int   i4_ext __attribute__((ext_vector_type(4)));
typedef int   i2_ext __attribute__((ext_vector_type(2)));

union H8I { i4_ext i; h8 h; };
union EDI { i2_ext i; Edge e; };

__device__ __forceinline__ float4 nt_load4(const float4* p) {
    f4_ext v = __builtin_nontemporal_load((const f4_ext*)p);
    return make_float4(v.x, v.y, v.z, v.w);
}
__device__ __forceinline__ void nt_store4(float4* p, float4 a) {
    f4_ext v = {a.x, a.y, a.z, a.w};
    __builtin_nontemporal_store(v, (f4_ext*)p);
}
__device__ __forceinline__ h8 nt_load_h8(const h8* p) {
    H8I u; u.i = __builtin_nontemporal_load((const i4_ext*)p);
    return u.h;
}
__device__ __forceinline__ Edge nt_load_edge(const Edge* p) {
    EDI u; u.i = __builtin_nontemporal_load((const i2_ext*)p);
    return u.e;
}

__device__ __forceinline__ h8 to_h8(float4 lo, float4 hi) {
    h8 r;
    r.a = __floats2half2_rn(lo.x, lo.y); r.b = __floats2half2_rn(lo.z, lo.w);
    r.c = __floats2half2_rn(hi.x, hi.y); r.d = __floats2half2_rn(hi.z, hi.w);
    return r;
}
__device__ __forceinline__ void h8_to_f(h8 h, float4& lo, float4& hi) {
    float2 p = __half22float2(h.a), q = __half22float2(h.b);
    float2 s = __half22float2(h.c), t = __half22float2(h.d);
    lo = make_float4(p.x, p.y, q.x, q.y);
    hi = make_float4(s.x, s.y, t.x, t.y);
}
__device__ __forceinline__ void fma4(float4& a, float v, float4 x) {
    a.x += v * x.x; a.y += v * x.y; a.z += v * x.z; a.w += v * x.w;
}
__device__ __forceinline__ float4 add4(float4 a, float4 b) {
    return make_float4(a.x + b.x, a.y + b.y, a.z + b.z, a.w + b.w);
}

// E16 = fp16(concat(uE, iE)); one work item = one h8 (2 float4 loads)
__device__ __forceinline__ void conv_do(int t, const float4* __restrict__ uE,
                                        const float4* __restrict__ iE,
                                        h8* __restrict__ E16) {
    if (t < 0 || t >= CONV_T) return;
    int f4i = t * 2;
    const int ub = USER_N * NV4;
    float4 lo, hi;
    if (f4i < ub) { lo = nt_load4(uE + f4i);        hi = nt_load4(uE + f4i + 1); }
    else          { lo = nt_load4(iE + (f4i - ub)); hi = nt_load4(iE + (f4i - ub) + 1); }
    E16[t] = to_h8(lo, hi);
}

// ---------------------------------------------------------------------------
// K2: histogram (blocks [0,HIST_BLK)) + conv chunk 0
// ---------------------------------------------------------------------------
__global__ void hist_convA(const int* __restrict__ ar, const int* __restrict__ ur,
                           int* __restrict__ cnt,
                           const float4* __restrict__ uE, const float4* __restrict__ iE,
                           h8* __restrict__ E16) {
    if (blockIdx.x < HIST_BLK) {
        int i = blockIdx.x * blockDim.x + threadIdx.x;
        if (i < N_EDGES_C)   atomicAdd(&cnt[ar[i]], 1);
        else if (i < NE_ALL) atomicAdd(&cnt[ur[i - N_EDGES_C] + N_TOTAL], 1);
    } else {
        conv_do((blockIdx.x - HIST_BLK) * 256 + (int)threadIdx.x, uE, iE, E16);
    }
}

// ---------------------------------------------------------------------------
// K3: per-block exclusive scan (blocks [0,SCANB_BLK)) + conv chunk 1
// ---------------------------------------------------------------------------
__global__ void scanblock_convB(const int* __restrict__ cnt,
                                int* __restrict__ rptr, int* __restrict__ bsum,
                                const float4* __restrict__ uE, const float4* __restrict__ iE,
                                h8* __restrict__ E16) {
    if (blockIdx.x < SCANB_BLK) {
        __shared__ int s[SCAN_B];
        int i = blockIdx.x * SCAN_B + threadIdx.x;
        int v = (i < NR_ALL) ? cnt[i] : 0;
        s[threadIdx.x] = v;
        __syncthreads();
        for (int off = 1; off < SCAN_B; off <<= 1) {
            int t = (threadIdx.x >= off) ? s[threadIdx.x - off] : 0;
            __syncthreads();
            s[threadIdx.x] += t;
            __syncthreads();
        }
        if (i < NR_ALL) rptr[i] = s[threadIdx.x] - v;
        if (threadIdx.x == SCAN_B - 1) bsum[blockIdx.x] = s[threadIdx.x];
    } else {
        conv_do((blockIdx.x - SCANB_BLK) * 256 + (int)threadIdx.x + CONV_CS,
                uE, iE, E16);
    }
}

// K4: single-block scan of block sums (tiny)
__global__ void scan_bsum_kernel(int* __restrict__ bsum, int nb) {
    __shared__ int s[SCAN_B];
    __shared__ int carry;
    if (threadIdx.x == 0) carry = 0;
    __syncthreads();
    for (int base = 0; base < nb; base += SCAN_B) {
        int i = base + threadIdx.x;
        int v = (i < nb) ? bsum[i] : 0;
        s[threadIdx.x] = v;
        __syncthreads();
        for (int off = 1; off < SCAN_B; off <<= 1) {
            int t = (threadIdx.x >= off) ? s[threadIdx.x - off] : 0;
            __syncthreads();
            s[threadIdx.x] += t;
            __syncthreads();
        }
        if (i < nb) bsum[i] = s[threadIdx.x] - v + carry;
        __syncthreads();
        if (threadIdx.x == 0) carry += s[SCAN_B - 1];
        __syncthreads();
    }
}

// ---------------------------------------------------------------------------
// K5: add block prefixes, init cursor (blocks [0,SCANB_BLK)) + conv chunk 2
// ---------------------------------------------------------------------------
__global__ void scanadd_convC(int* __restrict__ rptr, const int* __restrict__ bsum,
                              int* __restrict__ cursor,
                              const float4* __restrict__ uE, const float4* __restrict__ iE,
                              h8* __restrict__ E16) {
    if (blockIdx.x < SCANB_BLK) {
        int i = blockIdx.x * blockDim.x + threadIdx.x;
        if (i < NR_ALL) {
            int v = rptr[i] + bsum[i / SCAN_B];
            rptr[i]   = v;
            cursor[i] = v;
        }
        if (i == 0) rptr[NR_ALL] = NE_ALL;
    } else {
        conv_do((blockIdx.x - SCANB_BLK) * 256 + (int)threadIdx.x + 2 * CONV_CS,
                uE, iE, E16);
    }
}

// ---------------------------------------------------------------------------
// K6: scatter edges into CSR order (blocks [0,HIST_BLK)) + conv chunk 3
// ---------------------------------------------------------------------------
__global__ void scatter_convD(const int* __restrict__ ar, const int* __restrict__ ac,
                              const float* __restrict__ av,
                              const int* __restrict__ ur, const int* __restrict__ uc,
                              const float* __restrict__ uv,
                              int* __restrict__ cursor, Edge* __restrict__ edges,
                              const float4* __restrict__ uE, const float4* __restrict__ iE,
                              h8* __restrict__ E16) {
    if (blockIdx.x < HIST_BLK) {
        int i = blockIdx.x * blockDim.x + threadIdx.x;
        int r; Edge ed;
        if (i < N_EDGES_C)   { r = ar[i];             ed.c = ac[i];           ed.v = av[i]; }
        else if (i < NE_ALL) { int j = i - N_EDGES_C; r = ur[j] + N_TOTAL; ed.c = uc[j] + N_TOTAL; ed.v = uv[j]; }
        else return;
        int pos = atomicAdd(&cursor[r], 1);
        edges[pos] = ed;
    } else {
        conv_do((blockIdx.x - HIST_BLK) * 256 + (int)threadIdx.x + 3 * CONV_CS,
                uE, iE, E16);
    }
}

// row/col -> row in E16 (user-graph rows/cols shifted by N_TOTAL)
__device__ __forceinline__ int e16_row(int c) {
    return (c < N_TOTAL) ? c : c - N_TOTAL;
}

// ---------------------------------------------------------------------------
// Factorization: I+A+A^2+A^3 = (I+A^2)(I+A).
// pass1: w = e0_own + A*e0   (own-row add fused; w is pass2's gather table)
// ---------------------------------------------------------------------------
__global__ void spmm_pass1(const int* __restrict__ rptr,
                           const Edge* __restrict__ edges,
                           const h8* __restrict__ E16,
                           h8* __restrict__ w) {
    int t = blockIdx.x * blockDim.x + threadIdx.x;
    int r = t >> 4, sub = t & 15;
    if (r >= NR_ALL) return;
    int e0 = rptr[r], e1 = rptr[r + 1];

    // start from own row: w = e0[own] + sum(val * e0[col])
    float4 a0l, a0h;
    h8_to_f(E16[(size_t)e16_row(r) * NV8 + sub], a0l, a0h);
    float4 a1l = make_float4(0,0,0,0), a1h = a1l;

    int e = e0;
    for (; e + 2 <= e1; e += 2) {
        Edge d0 = edges[e], d1 = edges[e + 1];
        h8 h0 = E16[(size_t)e16_row(d0.c) * NV8 + sub];
        h8 h1 = E16[(size_t)e16_row(d1.c) * NV8 + sub];
        float4 lo, hi;
        h8_to_f(h0, lo, hi); fma4(a0l, d0.v, lo); fma4(a0h, d0.v, hi);
        h8_to_f(h1, lo, hi); fma4(a1l, d1.v, lo); fma4(a1h, d1.v, hi);
    }
    if (e < e1) {
        Edge d0 = edges[e];
        h8 h0 = E16[(size_t)e16_row(d0.c) * NV8 + sub];
        float4 lo, hi;
        h8_to_f(h0, lo, hi); fma4(a0l, d0.v, lo); fma4(a0h, d0.v, hi);
    }
    w[(size_t)r * NV8 + sub] = to_h8(add4(a0l, a1l), add4(a0h, a1h));
}

// ---------------------------------------------------------------------------
// pass2: tbuf = A*w (gather w, cached). Main rows -> tbuf (cached store: it is
// pass3's gather table). User rows: uacc = u0 + t  (t = U*(u0+U*u0) = Uu0+U^2u0).
// ---------------------------------------------------------------------------
__global__ void spmm_pass2(const int* __restrict__ rptr,
                           const Edge* __restrict__ edges,
                           const h8* __restrict__ w,
                           const h8* __restrict__ E16,
                           h8* __restrict__ tbuf,
                           float4* __restrict__ uacc) {
    int t = blockIdx.x * blockDim.x + threadIdx.x;
    int r = t >> 4, sub = t & 15;
    if (r >= NR_ALL) return;
    int e0 = rptr[r], e1 = rptr[r + 1];

    float4 a0l = make_float4(0,0,0,0), a0h = a0l, a1l = a0l, a1h = a0l;
    int e = e0;
    for (; e + 2 <= e1; e += 2) {
        Edge d0 = edges[e], d1 = edges[e + 1];
        h8 h0 = w[(size_t)d0.c * NV8 + sub];
        h8 h1 = w[(size_t)d1.c * NV8 + sub];
        float4 lo, hi;
        h8_to_f(h0, lo, hi); fma4(a0l, d0.v, lo); fma4(a0h, d0.v, hi);
        h8_to_f(h1, lo, hi); fma4(a1l, d1.v, lo); fma4(a1h, d1.v, hi);
    }
    if (e < e1) {
        Edge d0 = edges[e];
        h8 h0 = w[(size_t)d0.c * NV8 + sub];
        float4 lo, hi;
        h8_to_f(h0, lo, hi); fma4(a0l, d0.v, lo); fma4(a0h, d0.v, hi);
    }
    float4 al = add4(a0l, a1l), ah = add4(a0h, a1h);

    size_t o = (size_t)r * NV8 + sub;
    if (r < N_TOTAL) {
        tbuf[o] = to_h8(al, ah);
    } else {
        int ur = r - N_TOTAL;
        float4 u0l, u0h;
        h8_to_f(nt_load_h8(E16 + (size_t)ur * NV8 + sub), u0l, u0h);
        size_t of4 = (size_t)ur * NV4 + sub * 2;
        nt_store4(uacc + of4,     add4(u0l, al));
        nt_store4(uacc + of4 + 1, add4(u0h, ah));
    }
}

// ---------------------------------------------------------------------------
// pass3 (main rows): acc = w + A*tbuf  (gather tbuf cached; w/edges last-use
// nt loads; acc nt f32 stores).  A*tbuf = A^2*w, so acc = (I+A^2)(I+A)e0.
// ---------------------------------------------------------------------------
__global__ void spmm_pass3(const int* __restrict__ rptr,
                           const Edge* __restrict__ edges,
                           const h8* __restrict__ tbuf,
                           const h8* __restrict__ w,
                           float4* __restrict__ acc) {
    int t = blockIdx.x * blockDim.x + threadIdx.x;
    int r = t >> 4, sub = t & 15;
    if (r >= N_TOTAL) return;
    int e0 = rptr[r], e1 = rptr[r + 1];

    float4 a0l = make_float4(0,0,0,0), a0h = a0l, a1l = a0l, a1h = a0l;
    int e = e0;
    for (; e + 2 <= e1; e += 2) {
        Edge d0 = nt_load_edge(edges + e), d1 = nt_load_edge(edges + e + 1);
        h8 h0 = tbuf[(size_t)d0.c * NV8 + sub];
        h8 h1 = tbuf[(size_t)d1.c * NV8 + sub];
        float4 lo, hi;
        h8_to_f(h0, lo, hi); fma4(a0l, d0.v, lo); fma4(a0h, d0.v, hi);
        h8_to_f(h1, lo, hi); fma4(a1l, d1.v, lo); fma4(a1h, d1.v, hi);
    }
    if (e < e1) {
        Edge d0 = nt_load_edge(edges + e);
        h8 h0 = tbuf[(size_t)d0.c * NV8 + sub];
        float4 lo, hi;
        h8_to_f(h0, lo, hi); fma4(a0l, d0.v, lo); fma4(a0h, d0.v, hi);
    }
    float4 al = add4(a0l, a1l), ah = add4(a0h, a1h);

    size_t o = (size_t)r * NV8 + sub;
    float4 wl, wh;
    h8_to_f(nt_load_h8(w + o), wl, wh);

    size_t of4 = (size_t)r * NV4 + sub * 2;
    nt_store4(acc + of4,     add4(wl, al));
    nt_store4(acc + of4 + 1, add4(wh, ah));
}

// ---------------------------------------------------------------------------
extern "C" void kernel_launch(void* const* d_in, const int* in_sizes, int n_in,
                              void* d_out, int out_size, void* d_ws, size_t ws_size,
                              hipStream_t stream) {
    const float* uE    = (const float*)d_in[0];
    const float* iE    = (const float*)d_in[1];
    const int*   arows = (const int*)  d_in[2];
    const int*   acols = (const int*)  d_in[3];
    const float* avals = (const float*)d_in[4];
    const int*   urows = (const int*)  d_in[5];
    const int*   ucols = (const int*)  d_in[6];
    const float* uvals = (const float*)d_in[7];

    float* acc  = (float*)d_out;                              // N_TOTAL x 128 f32
    float* uacc = acc + (size_t)N_TOTAL * LATDIM;             // USER_N x 128 f32

    // workspace layout
    h8*    E16  = (h8*)d_ws;                                  // N_TOTAL*NV8  (76.8 MB)
    h8*    w    = E16 + (size_t)N_TOTAL * NV8;                // NR_ALL*NV8   (102.4 MB)
    h8*    tbuf = w + (size_t)NR_ALL * NV8;                   // N_TOTAL*NV8  (76.8 MB)
    int*   cnt  = (int*)(tbuf + (size_t)N_TOTAL * NV8);       // NR_ALL
    int*   rptr = cnt + NR_ALL;                               // NR_ALL+1
    int*   curp = rptr + NR_ALL + 1;                          // NR_ALL
    int*   bsum = curp + NR_ALL;                              // 4096
    Edge*  edges = (Edge*)(bsum + 4096);                      // NE_ALL (7.2 MB)

    const int TB = 256;
    const float4* uE4 = (const float4*)uE;
    const float4* iE4 = (const float4*)iE;

    hipMemsetAsync(cnt, 0, NR_ALL * sizeof(int), stream);

    // ---- CSR build with conv (E16) hidden underneath ----
    hist_convA<<<HIST_BLK + CONV_BLK, TB, 0, stream>>>(arows, urows, cnt, uE4, iE4, E16);
    scanblock_convB<<<SCANB_BLK + CONV_BLK, SCAN_B, 0, stream>>>(cnt, rptr, bsum, uE4, iE4, E16);
    scan_bsum_kernel<<<1, SCAN_B, 0, stream>>>(bsum, SCANB_BLK);
    scanadd_convC<<<SCANB_BLK + CONV_BLK, TB, 0, stream>>>(rptr, bsum, curp, uE4, iE4, E16);
    scatter_convD<<<HIST_BLK + CONV_BLK, TB, 0, stream>>>(
        arows, acols, avals, urows, ucols, uvals, curp, edges, uE4, iE4, E16);

    // ---- three factored SpMM passes (16 lanes/row) ----
    {
        int threads = NR_ALL * NV8;
        int grid = (threads + TB - 1) / TB;
        spmm_pass1<<<grid, TB, 0, stream>>>(rptr, edges, E16, w);
        spmm_pass2<<<grid, TB, 0, stream>>>(rptr, edges, w, E16,
                                            tbuf, (float4*)uacc);
    }
    {
        int threads = N_TOTAL * NV8;
        int grid = (threads + TB - 1) / TB;
        spmm_pass3<<<grid, TB, 0, stream>>>(rptr, edges, tbuf, w,
                                            (float4*)acc);
    }
}